// Round 6
// baseline (45.031 us; speedup 1.0000x reference)
//
#include <hip/hip_runtime.h>
#include <math.h>

// Problem constants
#define LN 512
#define RN 4096
#define EN 32
#define FN 64

// Tiling: 128(l) x 128(r) pair tile per block, 4 waves, each wave owns a
// 4x4 grid of 16x16 MFMA tiles (64x64 quadrant). EH rbf steps per block.
// EH=4 -> 1024 blocks -> up to 4 blocks/CU resident for latency hiding.
// NOTE: __launch_bounds__ kept at (256,2) — the (256,4) variant changed
// codegen (VGPR+AGPR cap 128 < ~104+64 needed) and memory-faulted.
#define BLT 128
#define BRT 128
#define EH  4

#define K16LOG2E 23.083120654223415f   // 16*log2(e):  exp(-16 t^2) = exp2(-K*t^2)
#define MU_STEP (8.0f / 31.0f)

typedef _Float16 half8 __attribute__((ext_vector_type(8)));  // MFMA A/B frag (4 VGPR)
typedef __attribute__((ext_vector_type(4))) float f32x4;     // MFMA C/D frag

// LDS: 2 planes of 128 rows x 64 f16 (128B rows, XOR-swizzled)
#define APLANE 0
#define BPLANE (128 * 128)
#define LDS_BYTES (2 * 128 * 128)   // 32768

__global__ __launch_bounds__(256, 2) void ff_mfma(
    const float* __restrict__ lig_feat,   // [L][E][F]
    const float* __restrict__ rec_feat,   // [R][E][F]
    const float* __restrict__ lig_coord,  // [L][3]
    const float* __restrict__ rec_coord,  // [R][3]
    float* __restrict__ partial)
{
    extern __shared__ char lds[];

    const int tid  = threadIdx.x;
    const int lane = tid & 63;
    const int w    = tid >> 6;
    const int wl   = (w >> 1) * 4;     // wave's base tile-row (of 8)
    const int wr   = (w & 1) * 4;      // wave's base tile-col (of 8)
    const int lrow = lane & 15;        // A-row / B-col within 16x16 tile
    const int lk   = lane >> 4;        // k-group 0..3

    const int l0 = blockIdx.y * BLT;
    const int r0 = blockIdx.x * BRT;
    const int e0 = blockIdx.z * EH;

    // ---- distances, computed once, reused for all EH steps ----
    // C/D layout (m89-verified): col = lane&15 (-> r), row = (lane>>4)*4 + reg (-> l)
    float rcx[4], rcy[4], rcz[4];
    #pragma unroll
    for (int tj = 0; tj < 4; ++tj) {
        const int r = r0 + (wr + tj) * 16 + lrow;
        rcx[tj] = rec_coord[r * 3 + 0];
        rcy[tj] = rec_coord[r * 3 + 1];
        rcz[tj] = rec_coord[r * 3 + 2];
    }
    float d[4][4][4];   // [ti][tj][reg]
    #pragma unroll
    for (int ti = 0; ti < 4; ++ti) {
        #pragma unroll
        for (int i = 0; i < 4; ++i) {
            const int l = l0 + (wl + ti) * 16 + lk * 4 + i;
            const float lx = lig_coord[l * 3 + 0];
            const float ly = lig_coord[l * 3 + 1];
            const float lz = lig_coord[l * 3 + 2];
            #pragma unroll
            for (int tj = 0; tj < 4; ++tj) {
                const float dx = lx - rcx[tj];
                const float dy = ly - rcy[tj];
                const float dz = lz - rcz[tj];
                d[ti][tj][i] = sqrtf(fmaf(dx, dx, fmaf(dy, dy, dz * dz)));
            }
        }
    }

    float usum = 0.0f;

    for (int ee = 0; ee < EH; ++ee) {
        const int e = e0 + ee;

        __syncthreads();   // previous iteration's readers done

        // ---- stage: fp32 -> f16 planes (RTE), XOR-swizzled rows ----
        // 4096 float4 per (block,e): 16 per thread. k<8 -> lig, k>=8 -> rec.
        #pragma unroll
        for (int k = 0; k < 16; ++k) {
            const int idx = k * 256 + tid;
            const int row = (idx >> 4) & 127;
            const int c   = idx & 15;
            const float4 v = (k < 8)
                ? *(const float4*)&lig_feat[((l0 + row) * EN + e) * FN + c * 4]
                : *(const float4*)&rec_feat[((r0 + row) * EN + e) * FN + c * 4];

            const unsigned short h0 = __builtin_bit_cast(unsigned short, (_Float16)v.x);
            const unsigned short h1 = __builtin_bit_cast(unsigned short, (_Float16)v.y);
            const unsigned short h2 = __builtin_bit_cast(unsigned short, (_Float16)v.z);
            const unsigned short h3 = __builtin_bit_cast(unsigned short, (_Float16)v.w);
            uint2 hw;
            hw.x = (unsigned)h0 | ((unsigned)h1 << 16);
            hw.y = (unsigned)h2 | ((unsigned)h3 << 16);

            const int off = row * 128 + ((c * 8) ^ ((row & 7) << 4));
            *(uint2*)(lds + ((k < 8) ? APLANE : BPLANE) + off) = hw;
        }
        __syncthreads();

        // ---- single-product f16 MFMA over f=64 (2 k-chunks of 32) ----
        f32x4 acc[4][4];
        #pragma unroll
        for (int ti = 0; ti < 4; ++ti)
            #pragma unroll
            for (int tj = 0; tj < 4; ++tj)
                acc[ti][tj] = (f32x4){0.f, 0.f, 0.f, 0.f};

        #pragma unroll
        for (int kc = 0; kc < 2; ++kc) {
            const int inrow = (kc * 64 + lk * 16) ^ ((lrow & 7) << 4);
            half8 af[4], bf_[4];
            #pragma unroll
            for (int t = 0; t < 4; ++t) {
                const int arow = (wl + t) * 16 + lrow;
                const int brow = (wr + t) * 16 + lrow;
                af[t]  = *(const half8*)(lds + APLANE + arow * 128 + inrow);
                bf_[t] = *(const half8*)(lds + BPLANE + brow * 128 + inrow);
            }
            #pragma unroll
            for (int ti = 0; ti < 4; ++ti) {
                #pragma unroll
                for (int tj = 0; tj < 4; ++tj) {
                    acc[ti][tj] = __builtin_amdgcn_mfma_f32_16x16x32_f16(
                        af[ti], bf_[tj], acc[ti][tj], 0, 0, 0);
                }
            }
        }

        // ---- rbf weight + accumulate ----
        const float mu = (float)e * MU_STEP;
        #pragma unroll
        for (int ti = 0; ti < 4; ++ti) {
            #pragma unroll
            for (int tj = 0; tj < 4; ++tj) {
                #pragma unroll
                for (int i = 0; i < 4; ++i) {
                    const float t = d[ti][tj][i] - mu;
                    const float wgt = __builtin_amdgcn_exp2f(-K16LOG2E * t * t);
                    usum = fmaf(acc[ti][tj][i], wgt, usum);
                }
            }
        }
    }

    // ---- block reduction (reuse LDS) ----
    __syncthreads();
    float* red = (float*)lds;
    red[tid] = usum;
    __syncthreads();
    #pragma unroll
    for (int st = 128; st > 0; st >>= 1) {
        if (tid < st) red[tid] += red[tid + st];
        __syncthreads();
    }
    if (tid == 0) {
        const int bidx = (blockIdx.z * gridDim.y + blockIdx.y) * gridDim.x + blockIdx.x;
        partial[bidx] = red[0];
    }
}

__global__ __launch_bounds__(256) void ff_reduce(
    const float* __restrict__ partial, float* __restrict__ out, int n)
{
    __shared__ float s[256];
    float v = 0.0f;
    for (int i = threadIdx.x; i < n; i += 256) v += partial[i];
    s[threadIdx.x] = v;
    __syncthreads();
    #pragma unroll
    for (int st = 128; st > 0; st >>= 1) {
        if (threadIdx.x < st) s[threadIdx.x] += s[threadIdx.x + st];
        __syncthreads();
    }
    if (threadIdx.x == 0) out[0] = s[0] * 0.01f;
}

extern "C" void kernel_launch(void* const* d_in, const int* in_sizes, int n_in,
                              void* d_out, int out_size, void* d_ws, size_t ws_size,
                              hipStream_t stream)
{
    const float* lig_feat  = (const float*)d_in[0];
    const float* rec_feat  = (const float*)d_in[1];
    const float* lig_coord = (const float*)d_in[2];
    const float* rec_coord = (const float*)d_in[3];
    float* out = (float*)d_out;
    float* partial = (float*)d_ws;

    const dim3 grid(RN / BRT, LN / BLT, EN / EH);   // (32, 4, 8) = 1024 blocks
    ff_mfma<<<grid, dim3(256), LDS_BYTES, stream>>>(
        lig_feat, rec_feat, lig_coord, rec_coord, partial);

    const int nPartial = (RN / BRT) * (LN / BLT) * (EN / EH);   // 1024
    ff_reduce<<<1, 256, 0, stream>>>(partial, out, nPartial);
}

// Round 7
// 38.931 us; speedup vs baseline: 1.1567x; 1.1567x over previous
//
#include <hip/hip_runtime.h>
#include <math.h>

// Problem constants
#define LN 512
#define RN 4096
#define EN 32
#define FN 64

// Tiling: 128(l) x 128(r) pair tile per block, 512 threads = 8 waves.
// Wave tile = 32(l) x 64(r) = 2x4 grid of 16x16 MFMA tiles:
//   acc = 32 AGPR, d[] = 32 VGPR  -> total regs ~<=128 -> 4 waves/SIMD.
// EH=8 -> grid (32,4,4) = 512 blocks = 2 blocks/CU (16 waves/CU resident).
#define BLT 128
#define BRT 128
#define EH  8

#define K16LOG2E 23.083120654223415f   // 16*log2(e):  exp(-16 t^2) = exp2(-K*t^2)
#define MU_STEP (8.0f / 31.0f)

typedef _Float16 half8 __attribute__((ext_vector_type(8)));  // MFMA A/B frag (4 VGPR)
typedef __attribute__((ext_vector_type(4))) float f32x4;     // MFMA C/D frag

// LDS: 2 planes of 128 rows x 64 f16 (128B rows, XOR-swizzled)
#define APLANE 0
#define BPLANE (128 * 128)
#define LDS_BYTES (2 * 128 * 128)   // 32768

__global__ __launch_bounds__(512, 1) void ff_mfma(
    const float* __restrict__ lig_feat,   // [L][E][F]
    const float* __restrict__ rec_feat,   // [R][E][F]
    const float* __restrict__ lig_coord,  // [L][3]
    const float* __restrict__ rec_coord,  // [R][3]
    float* __restrict__ partial)
{
    extern __shared__ char lds[];

    const int tid  = threadIdx.x;
    const int lane = tid & 63;
    const int w    = tid >> 6;         // 0..7
    const int wl   = (w & 3) * 2;      // wave's base l-tile (0,2,4,6) of 8
    const int wr   = (w >> 2) * 4;     // wave's base r-tile (0,4) of 8
    const int lrow = lane & 15;        // A-row / B-col within 16x16 tile
    const int lk   = lane >> 4;        // k-group 0..3

    const int l0 = blockIdx.y * BLT;
    const int r0 = blockIdx.x * BRT;
    const int e0 = blockIdx.z * EH;

    // ---- distances, computed once, reused for all EH steps ----
    // C/D layout (m89-verified): col = lane&15 (-> r), row = (lane>>4)*4 + reg (-> l)
    float rcx[4], rcy[4], rcz[4];
    #pragma unroll
    for (int tj = 0; tj < 4; ++tj) {
        const int r = r0 + (wr + tj) * 16 + lrow;
        rcx[tj] = rec_coord[r * 3 + 0];
        rcy[tj] = rec_coord[r * 3 + 1];
        rcz[tj] = rec_coord[r * 3 + 2];
    }
    float d[2][4][4];   // [ti][tj][reg]
    #pragma unroll
    for (int ti = 0; ti < 2; ++ti) {
        #pragma unroll
        for (int i = 0; i < 4; ++i) {
            const int l = l0 + (wl + ti) * 16 + lk * 4 + i;
            const float lx = lig_coord[l * 3 + 0];
            const float ly = lig_coord[l * 3 + 1];
            const float lz = lig_coord[l * 3 + 2];
            #pragma unroll
            for (int tj = 0; tj < 4; ++tj) {
                const float dx = lx - rcx[tj];
                const float dy = ly - rcy[tj];
                const float dz = lz - rcz[tj];
                d[ti][tj][i] = sqrtf(fmaf(dx, dx, fmaf(dy, dy, dz * dz)));
            }
        }
    }

    float usum = 0.0f;

    for (int ee = 0; ee < EH; ++ee) {
        const int e = e0 + ee;

        __syncthreads();   // previous iteration's readers done

        // ---- stage: fp32 -> f16 planes (RTE), XOR-swizzled rows ----
        // 4096 float4 per (block,e): 8 per thread. k<4 -> lig, k>=4 -> rec.
        #pragma unroll
        for (int k = 0; k < 8; ++k) {
            const int idx = k * 512 + tid;
            const int row = (idx >> 4) & 127;
            const int c   = idx & 15;
            const float4 v = (k < 4)
                ? *(const float4*)&lig_feat[((l0 + row) * EN + e) * FN + c * 4]
                : *(const float4*)&rec_feat[((r0 + row) * EN + e) * FN + c * 4];

            const unsigned short h0 = __builtin_bit_cast(unsigned short, (_Float16)v.x);
            const unsigned short h1 = __builtin_bit_cast(unsigned short, (_Float16)v.y);
            const unsigned short h2 = __builtin_bit_cast(unsigned short, (_Float16)v.z);
            const unsigned short h3 = __builtin_bit_cast(unsigned short, (_Float16)v.w);
            uint2 hw;
            hw.x = (unsigned)h0 | ((unsigned)h1 << 16);
            hw.y = (unsigned)h2 | ((unsigned)h3 << 16);

            const int off = row * 128 + ((c * 8) ^ ((row & 7) << 4));
            *(uint2*)(lds + ((k < 4) ? APLANE : BPLANE) + off) = hw;
        }
        __syncthreads();

        // ---- single-product f16 MFMA over f=64 (2 k-chunks of 32) ----
        f32x4 acc[2][4];
        #pragma unroll
        for (int ti = 0; ti < 2; ++ti)
            #pragma unroll
            for (int tj = 0; tj < 4; ++tj)
                acc[ti][tj] = (f32x4){0.f, 0.f, 0.f, 0.f};

        #pragma unroll
        for (int kc = 0; kc < 2; ++kc) {
            const int inrow = (kc * 64 + lk * 16) ^ ((lrow & 7) << 4);
            half8 af[2], bf_[4];
            #pragma unroll
            for (int t = 0; t < 2; ++t) {
                const int arow = (wl + t) * 16 + lrow;
                af[t] = *(const half8*)(lds + APLANE + arow * 128 + inrow);
            }
            #pragma unroll
            for (int t = 0; t < 4; ++t) {
                const int brow = (wr + t) * 16 + lrow;
                bf_[t] = *(const half8*)(lds + BPLANE + brow * 128 + inrow);
            }
            #pragma unroll
            for (int ti = 0; ti < 2; ++ti) {
                #pragma unroll
                for (int tj = 0; tj < 4; ++tj) {
                    acc[ti][tj] = __builtin_amdgcn_mfma_f32_16x16x32_f16(
                        af[ti], bf_[tj], acc[ti][tj], 0, 0, 0);
                }
            }
        }

        // ---- rbf weight + accumulate ----
        const float mu = (float)e * MU_STEP;
        #pragma unroll
        for (int ti = 0; ti < 2; ++ti) {
            #pragma unroll
            for (int tj = 0; tj < 4; ++tj) {
                #pragma unroll
                for (int i = 0; i < 4; ++i) {
                    const float t = d[ti][tj][i] - mu;
                    const float wgt = __builtin_amdgcn_exp2f(-K16LOG2E * t * t);
                    usum = fmaf(acc[ti][tj][i], wgt, usum);
                }
            }
        }
    }

    // ---- block reduction (reuse LDS) ----
    __syncthreads();
    float* red = (float*)lds;
    red[tid] = usum;
    __syncthreads();
    #pragma unroll
    for (int st = 256; st > 0; st >>= 1) {
        if (tid < st) red[tid] += red[tid + st];
        __syncthreads();
    }
    if (tid == 0) {
        const int bidx = (blockIdx.z * gridDim.y + blockIdx.y) * gridDim.x + blockIdx.x;
        partial[bidx] = red[0];
    }
}

__global__ __launch_bounds__(256) void ff_reduce(
    const float* __restrict__ partial, float* __restrict__ out, int n)
{
    __shared__ float s[256];
    float v = 0.0f;
    for (int i = threadIdx.x; i < n; i += 256) v += partial[i];
    s[threadIdx.x] = v;
    __syncthreads();
    #pragma unroll
    for (int st = 128; st > 0; st >>= 1) {
        if (threadIdx.x < st) s[threadIdx.x] += s[threadIdx.x + st];
        __syncthreads();
    }
    if (threadIdx.x == 0) out[0] = s[0] * 0.01f;
}

extern "C" void kernel_launch(void* const* d_in, const int* in_sizes, int n_in,
                              void* d_out, int out_size, void* d_ws, size_t ws_size,
                              hipStream_t stream)
{
    const float* lig_feat  = (const float*)d_in[0];
    const float* rec_feat  = (const float*)d_in[1];
    const float* lig_coord = (const float*)d_in[2];
    const float* rec_coord = (const float*)d_in[3];
    float* out = (float*)d_out;
    float* partial = (float*)d_ws;

    const dim3 grid(RN / BRT, LN / BLT, EN / EH);   // (32, 4, 4) = 512 blocks
    ff_mfma<<<grid, dim3(512), LDS_BYTES, stream>>>(
        lig_feat, rec_feat, lig_coord, rec_coord, partial);

    const int nPartial = (RN / BRT) * (LN / BLT) * (EN / EH);   // 512
    ff_reduce<<<1, 256, 0, stream>>>(partial, out, nPartial);
}